// Round 12
// baseline (552.057 us; speedup 1.0000x reference)
//
#include <hip/hip_runtime.h>
#include <hip/hip_bf16.h>

#define S_CNT 250
#define N_PED 200
#define MAXP  16
#define HID   512
#define BN    32

// d_ws layout (bytes): ws1 frags [pass8][nt4][ks4][lane64] short8 = 131072
//                      ws2 frags [pass8][kcl2][nt2][lane64] short8 = 32768
//                      WaT [t16][k512] fp32 = 32768            total 196608
#define WS1_FRAGS 8192
#define WS2_FRAGS 2048
#define WS_NEED   196608u

typedef __attribute__((ext_vector_type(8))) short short8;
typedef __attribute__((ext_vector_type(4))) float floatx4;

__device__ __forceinline__ short f2bu(float f) {
    union { __hip_bfloat16 h; unsigned short u; } c;
    c.h = __float2bfloat16(f);
    return (short)c.u;
}

// ---- one-time weight convert + swizzle into workspace (runs every launch) ----
__global__ __launch_bounds__(256) void cvt_kernel(
    const float* __restrict__ W1, const float* __restrict__ W2,
    const float* __restrict__ Wa, short8* __restrict__ ws1,
    short8* __restrict__ ws2, float* __restrict__ WaT)
{
    int t = blockIdx.x * 256 + threadIdx.x;
    if (t < WS1_FRAGS) {
        int lane = t & 63, ks = (t >> 6) & 3, nt = (t >> 8) & 3, pass = t >> 10;
        int n  = pass * 64 + nt * 16 + (lane & 15);
        int k0 = ks * 32 + ((lane >> 4) << 3);
        short8 v;
#pragma unroll
        for (int j = 0; j < 8; ++j) v[j] = f2bu(W1[(k0 + j) * HID + n]);
        ws1[t] = v;
    } else if (t < WS1_FRAGS + WS2_FRAGS) {
        int t2 = t - WS1_FRAGS;
        int lane = t2 & 63, nt2 = (t2 >> 6) & 1, kcl = (t2 >> 7) & 1, pass = t2 >> 8;
        int kc = pass * 2 + kcl;
        int n  = nt2 * 16 + (lane & 15);
        int k0 = kc * 32 + ((lane >> 4) << 3);
        short8 v;
#pragma unroll
        for (int j = 0; j < 8; ++j) v[j] = f2bu(W2[(k0 + j) * BN + n]);
        ws2[t2] = v;
    } else {
        int t3 = t - WS1_FRAGS - WS2_FRAGS;       // 2048 threads x float4
#pragma unroll
        for (int i = 0; i < 4; ++i) {
            int e = t3 * 4 + i, tt = e >> 9, k = e & 511;
            WaT[e] = Wa[k * MAXP + tt];
        }
    }
}

// Block = 4 waves, 8 peds (2/wave, same sequence). 8 passes of 64 stage-1 cols.
// Occupancy: r8-r11 showed achieved blocks/CU tracks the waves-per-eu attribute,
// not resources (launch_bounds(.,2)->22.5%, (.,4)->43.8% but allocator overshot
// to 8 waves/EU -> VGPR 64 -> 950MB spill). Pin the window: waves_per_eu(4,4)
// caps allocator at 512/4=128 VGPR (state needs ~104 -> no spill) and yields
// 4 blocks/CU (4 x 36.3KB LDS = 145KB < 160KB).
template<bool PRE>
__global__ __launch_bounds__(256)
__attribute__((amdgpu_waves_per_eu(4, 4))) void fused_kernel(
    const float* __restrict__ h_states, const float* __restrict__ last_pos,
    const float* __restrict__ Wpos,     const float* __restrict__ bpos,
    const float* __restrict__ W1,       const float* __restrict__ b1,
    const float* __restrict__ W2,       const float* __restrict__ b2,
    const float* __restrict__ Wa,       const float* __restrict__ ba,
    const short8* __restrict__ ws1,     const short8* __restrict__ ws2,
    const float* __restrict__ WaT,      float* __restrict__ out)
{
    __shared__ short8 fb1[1024];               // [nt 4][ks 4][lane 64]  16 KB
    __shared__ short8 fb2[256];                // [kcl 2][nt2 2][lane 64] 4 KB
    __shared__ unsigned short X1c[4][16][40];  // bf16, row padded 32->40  5 KB
    __shared__ float X2s[4][512];              // per-wave X2 [16][32]    8 KB
    __shared__ float px[N_PED], py[N_PED];     // 1.6 KB
    __shared__ float LG[4][16], WS[4][16];     // 0.5 KB  (total ~35.9 KB)

    const int tid = threadIdx.x;
    const int wv  = tid >> 6;
    const int ln  = tid & 63;
    const int q8  = (ln >> 4) << 3;
    const int c15 = ln & 15;
    const int s    = blockIdx.x / 25;          // 25 blocks per sequence
    const int base = s * N_PED;
    const int il0  = (blockIdx.x % 25) * 8 + wv * 2;

    if (tid < N_PED) {
        px[tid] = last_pos[(base + tid) * 2 + 0];
        py[tid] = last_pos[(base + tid) * 2 + 1];
    }
    __syncthreads();

    // ---- per-ped selection (round-8-verified) + A-fragment build ----
    short8  af[2][4];
    floatx4 c2[2][2] = {};
    for (int pedi = 0; pedi < 2; ++pedi) {
        const int il = il0 + pedi;
        const float xi = px[il], yi = py[il];
        const int mm = c15, qq = ln >> 4;
        int cnt;
        {
            float dxm = __fsub_rn(px[mm], xi), dym = __fsub_rn(py[mm], yi);
            float dm = __fsqrt_rn(__builtin_fmaf(dxm, dxm, __fmul_rn(dym, dym)));
            cnt = 0;
            for (int j = qq * 50; j < qq * 50 + 50; ++j) {
                float dx = __fsub_rn(px[j], xi), dy = __fsub_rn(py[j], yi);
                float dj = __fsqrt_rn(__builtin_fmaf(dx, dx, __fmul_rn(dy, dy)));
                cnt += (dj < dm || (dj == dm && j < mm)) ? 1 : 0;
            }
            cnt += __shfl_xor(cnt, 16, 64);
            cnt += __shfl_xor(cnt, 32, 64);    // lane ln holds rank(ln&15)
        }
        const int sm = cnt;
#pragma unroll
        for (int ks = 0; ks < 2; ++ks) {       // k 0..63: h_sel
            const float* hp = &h_states[(base + sm) * 64 + ks * 32 + q8];
            short8 v;
#pragma unroll
            for (int j = 0; j < 8; ++j) v[j] = f2bu(hp[j]);
            af[pedi][ks] = v;
        }
        const float fx = px[sm] - xi, fy = py[sm] - yi;
#pragma unroll
        for (int ks = 2; ks < 4; ++ks) {       // k 64..127: pos embedding
            int e0 = (ks - 2) * 32 + q8;
            short8 v;
#pragma unroll
            for (int j = 0; j < 8; ++j) {
                float e = fx * Wpos[e0 + j] + fy * Wpos[64 + e0 + j] + bpos[e0 + j];
                v[j] = f2bu(e);
            }
            af[pedi][ks] = v;
        }
    }

    // ---- main loop: 8 passes x 4 stage-1 N-tiles ----
    for (int p = 0; p < 8; ++p) {
        __syncthreads();                       // prior pass's fb reads complete
        if (PRE) {
#pragma unroll
            for (int it = 0; it < 4; ++it)
                fb1[it * 256 + tid] = ws1[p * 1024 + it * 256 + tid];
            fb2[tid] = ws2[p * 256 + tid];
        } else {
            for (int f = tid; f < 1024; f += 256) {
                int lane = f & 63, ks = (f >> 6) & 3, nt = f >> 8;
                int n  = p * 64 + nt * 16 + (lane & 15);
                int k0 = ks * 32 + ((lane >> 4) << 3);
                short8 v;
#pragma unroll
                for (int j = 0; j < 8; ++j) v[j] = f2bu(W1[(k0 + j) * HID + n]);
                fb1[f] = v;
            }
            {
                int lane = tid & 63, nt2 = (tid >> 6) & 1, kcl = tid >> 7;
                int kc = p * 2 + kcl;
                int n  = nt2 * 16 + (lane & 15);
                int k0 = kc * 32 + ((lane >> 4) << 3);
                short8 v;
#pragma unroll
                for (int j = 0; j < 8; ++j) v[j] = f2bu(W2[(k0 + j) * BN + n]);
                fb2[tid] = v;
            }
        }
        __syncthreads();
#pragma unroll
        for (int pedi = 0; pedi < 2; ++pedi) {
#pragma unroll
            for (int ntl = 0; ntl < 4; ++ntl) {
                const int nt = p * 4 + ntl;
                floatx4 c = {};
#pragma unroll
                for (int ks = 0; ks < 4; ++ks)
                    c = __builtin_amdgcn_mfma_f32_16x16x32_bf16(
                            af[pedi][ks], fb1[ntl * 256 + ks * 64 + ln], c, 0, 0, 0);
                // C layout: col = ln&15, row = (ln>>4)*4 + r
                const float bb = b1[nt * 16 + c15];
                const int colb = (ntl & 1) * 16 + c15;
#pragma unroll
                for (int r = 0; r < 4; ++r)
                    X1c[wv][(ln >> 4) * 4 + r][colb] =
                        (unsigned short)f2bu(fmaxf(c[r] + bb, 0.f));
                if (ntl & 1) {                 // 32-col X1 chunk ready
                    const int kcl = ntl >> 1;
                    short8 a2 = *(const short8*)&X1c[wv][c15][q8];
                    c2[pedi][0] = __builtin_amdgcn_mfma_f32_16x16x32_bf16(
                            a2, fb2[kcl * 128 + ln], c2[pedi][0], 0, 0, 0);
                    c2[pedi][1] = __builtin_amdgcn_mfma_f32_16x16x32_bf16(
                            a2, fb2[kcl * 128 + 64 + ln], c2[pedi][1], 0, 0, 0);
                }
            }
        }
    }

    // ---- epilogue per ped (round-9 verified logic; WaT float4 when PRE) ----
    for (int pedi = 0; pedi < 2; ++pedi) {
#pragma unroll
        for (int nt2 = 0; nt2 < 2; ++nt2) {
            const float bb2 = b2[nt2 * 16 + c15];
#pragma unroll
            for (int r = 0; r < 4; ++r)
                X2s[wv][((ln >> 4) * 4 + r) * 32 + nt2 * 16 + c15] =
                    fmaxf(c2[pedi][nt2][r] + bb2, 0.f);
        }
        {
            int t = c15, g = ln >> 4;
            float lg = 0.f;
            if (PRE) {
                const float4* wp = (const float4*)&WaT[t * 512 + g * 128];
                for (int kk = 0; kk < 32; ++kk) {
                    float4 w = wp[kk];
                    const float* xp = &X2s[wv][g * 128 + kk * 4];
                    lg += xp[0] * w.x + xp[1] * w.y + xp[2] * w.z + xp[3] * w.w;
                }
            } else {
                for (int k = g * 128; k < g * 128 + 128; ++k)
                    lg += X2s[wv][k] * Wa[k * MAXP + t];
            }
            lg += __shfl_xor(lg, 16, 64);
            lg += __shfl_xor(lg, 32, 64);
            if (ln < 16) LG[wv][ln] = lg + ba[ln];
        }
        float mx = -1e30f;
#pragma unroll
        for (int m = 0; m < MAXP; ++m) mx = fmaxf(mx, LG[wv][m]);
        float sum = 0.f;
#pragma unroll
        for (int m = 0; m < MAXP; ++m) sum += expf(LG[wv][m] - mx);
        if (ln < 16) WS[wv][ln] = expf(LG[wv][ln] - mx) / sum;
        if (ln < BN) {
            float o = 0.f;
#pragma unroll
            for (int m = 0; m < MAXP; ++m) o += WS[wv][m] * X2s[wv][m * BN + ln];
            out[(base + il0 + pedi) * BN + ln] = o;
        }
    }
}

extern "C" void kernel_launch(void* const* d_in, const int* in_sizes, int n_in,
                              void* d_out, int out_size, void* d_ws, size_t ws_size,
                              hipStream_t stream) {
    const float* h_states = (const float*)d_in[0];
    const float* last_pos = (const float*)d_in[1];
    const float* Wpos     = (const float*)d_in[2];
    const float* bpos     = (const float*)d_in[3];
    const float* W1       = (const float*)d_in[4];
    const float* b1       = (const float*)d_in[5];
    const float* W2       = (const float*)d_in[6];
    const float* b2       = (const float*)d_in[7];
    const float* Wa       = (const float*)d_in[8];
    const float* ba       = (const float*)d_in[9];
    // d_in[10] seq_start_end, d_in[11] train_or_test: structurally constant, unused

    short8* ws1 = (short8*)d_ws;
    short8* ws2 = ws1 + WS1_FRAGS;
    float*  WaT = (float*)(ws2 + WS2_FRAGS);
    const int grid = (S_CNT * N_PED) / 8;      // 6250

    if (ws_size >= WS_NEED) {
        cvt_kernel<<<48, 256, 0, stream>>>(W1, W2, Wa, ws1, ws2, WaT);
        fused_kernel<true><<<grid, 256, 0, stream>>>(
            h_states, last_pos, Wpos, bpos, W1, b1, W2, b2, Wa, ba,
            ws1, ws2, WaT, (float*)d_out);
    } else {
        fused_kernel<false><<<grid, 256, 0, stream>>>(
            h_states, last_pos, Wpos, bpos, W1, b1, W2, b2, Wa, ba,
            ws1, ws2, WaT, (float*)d_out);
    }
}

// Round 13
// 319.947 us; speedup vs baseline: 1.7255x; 1.7255x over previous
//
#include <hip/hip_runtime.h>
#include <hip/hip_bf16.h>

#define S_CNT 250
#define N_PED 200
#define MAXP  16
#define HID   512
#define BN    32

// d_ws layout: ws1 frags [pass8][ntl4][ks4][lane64] short8 = 131072 B
//              ws2 frags [pass8][kcl2][nt2][lane64] short8 =  32768 B
#define WS1_FRAGS 8192
#define WS2_FRAGS 2048
#define WS_NEED   163840u

typedef __attribute__((ext_vector_type(8))) short short8;
typedef __attribute__((ext_vector_type(4))) float floatx4;

__device__ __forceinline__ short f2bu(float f) {
    union { __hip_bfloat16 h; unsigned short u; } c;
    c.h = __float2bfloat16(f);
    return (short)c.u;
}

// ---- one-time weight convert + swizzle into workspace ----
__global__ __launch_bounds__(256) void cvt_kernel(
    const float* __restrict__ W1, const float* __restrict__ W2,
    short8* __restrict__ ws1, short8* __restrict__ ws2)
{
    int t = blockIdx.x * 256 + threadIdx.x;
    if (t < WS1_FRAGS) {
        int lane = t & 63, ks = (t >> 6) & 3, nt = (t >> 8) & 3, pass = t >> 10;
        int n  = pass * 64 + nt * 16 + (lane & 15);
        int k0 = ks * 32 + ((lane >> 4) << 3);
        short8 v;
#pragma unroll
        for (int j = 0; j < 8; ++j) v[j] = f2bu(W1[(k0 + j) * HID + n]);
        ws1[t] = v;
    } else if (t < WS1_FRAGS + WS2_FRAGS) {
        int t2 = t - WS1_FRAGS;
        int lane = t2 & 63, nt2 = (t2 >> 6) & 1, kcl = (t2 >> 7) & 1, pass = t2 >> 8;
        int kc = pass * 2 + kcl;
        int n  = nt2 * 16 + (lane & 15);
        int k0 = kc * 32 + ((lane >> 4) << 3);
        short8 v;
#pragma unroll
        for (int j = 0; j < 8; ++j) v[j] = f2bu(W2[(k0 + j) * BN + n]);
        ws2[t2] = v;
    }
}

// Block = 4 waves, 8 peds (2/wave, same sequence). B-fragments stream DIRECTLY
// from pre-swizzled global (L1/L2-served, VMEM pipe) -> no fb LDS buffers, no
// main-loop barriers (X1c transpose is wave-private). B-frags hoisted across
// the 2 peds. r8-r12 lesson: 2-ped state can't fit 128 total regs -> stay at
// 2 blocks/CU (launch_bounds(256,2), no spill) and unload the LDS pipe instead.
__global__ __launch_bounds__(256, 2) void fused_pre(
    const float* __restrict__ h_states, const float* __restrict__ last_pos,
    const float* __restrict__ Wpos,     const float* __restrict__ bpos,
    const float* __restrict__ b1,       const float* __restrict__ b2,
    const float* __restrict__ Wa,       const float* __restrict__ ba,
    const short8* __restrict__ ws1,     const short8* __restrict__ ws2,
    float* __restrict__ out)
{
    __shared__ unsigned short X1c[4][2][16][42];   // per-wave, per-ped; pad 42
    __shared__ float X2s[4][512];                  // per-wave X2 [16][32]
    __shared__ float px[N_PED], py[N_PED];
    __shared__ float LG[4][16], WS[4][16];         // total ~20.4 KB

    const int tid = threadIdx.x;
    const int wv  = tid >> 6;
    const int ln  = tid & 63;
    const int q8  = (ln >> 4) << 3;
    const int c15 = ln & 15;
    const int s    = blockIdx.x / 25;
    const int base = s * N_PED;
    const int il0  = (blockIdx.x % 25) * 8 + wv * 2;

    if (tid < N_PED) {
        px[tid] = last_pos[(base + tid) * 2 + 0];
        py[tid] = last_pos[(base + tid) * 2 + 1];
    }
    __syncthreads();                               // the only block barrier

    // ---- per-ped selection (r8-verified) + A-fragment build ----
    short8  af[2][4];
    floatx4 c2[2][2] = {};
    for (int pedi = 0; pedi < 2; ++pedi) {
        const int il = il0 + pedi;
        const float xi = px[il], yi = py[il];
        const int mm = c15, qq = ln >> 4;
        int cnt;
        {
            float dxm = __fsub_rn(px[mm], xi), dym = __fsub_rn(py[mm], yi);
            float dm = __fsqrt_rn(__builtin_fmaf(dxm, dxm, __fmul_rn(dym, dym)));
            cnt = 0;
            for (int j = qq * 50; j < qq * 50 + 50; ++j) {
                float dx = __fsub_rn(px[j], xi), dy = __fsub_rn(py[j], yi);
                float dj = __fsqrt_rn(__builtin_fmaf(dx, dx, __fmul_rn(dy, dy)));
                cnt += (dj < dm || (dj == dm && j < mm)) ? 1 : 0;
            }
            cnt += __shfl_xor(cnt, 16, 64);
            cnt += __shfl_xor(cnt, 32, 64);        // lane ln holds rank(ln&15)
        }
        const int sm = cnt;
#pragma unroll
        for (int ks = 0; ks < 2; ++ks) {           // k 0..63: h_sel
            const float* hp = &h_states[(base + sm) * 64 + ks * 32 + q8];
            short8 v;
#pragma unroll
            for (int j = 0; j < 8; ++j) v[j] = f2bu(hp[j]);
            af[pedi][ks] = v;
        }
        const float fx = px[sm] - xi, fy = py[sm] - yi;
#pragma unroll
        for (int ks = 2; ks < 4; ++ks) {           // k 64..127: pos embedding
            int e0 = (ks - 2) * 32 + q8;
            short8 v;
#pragma unroll
            for (int j = 0; j < 8; ++j) {
                float e = fx * Wpos[e0 + j] + fy * Wpos[64 + e0 + j] + bpos[e0 + j];
                v[j] = f2bu(e);
            }
            af[pedi][ks] = v;
        }
    }

    // ---- main loop: 8 passes x 4 n-tiles, no barriers ----
    for (int p = 0; p < 8; ++p) {
#pragma unroll
        for (int ntl = 0; ntl < 4; ++ntl) {
            const int nt = p * 4 + ntl;
            short8 bf[4];                          // B-frags, shared by both peds
#pragma unroll
            for (int ks = 0; ks < 4; ++ks)
                bf[ks] = ws1[p * 1024 + ntl * 256 + ks * 64 + ln];
            const float bb = b1[nt * 16 + c15];
            const int colb = (ntl & 1) * 16 + c15;
#pragma unroll
            for (int pedi = 0; pedi < 2; ++pedi) {
                floatx4 c = {};
#pragma unroll
                for (int ks = 0; ks < 4; ++ks)
                    c = __builtin_amdgcn_mfma_f32_16x16x32_bf16(
                            af[pedi][ks], bf[ks], c, 0, 0, 0);
                // C layout: col = ln&15, row = (ln>>4)*4 + r
#pragma unroll
                for (int r = 0; r < 4; ++r)
                    X1c[wv][pedi][(ln >> 4) * 4 + r][colb] =
                        (unsigned short)f2bu(fmaxf(c[r] + bb, 0.f));
            }
            if (ntl & 1) {                         // 32-col X1 chunks ready
                const int kcl = ntl >> 1;
                short8 w20 = ws2[p * 256 + kcl * 128 + ln];
                short8 w21 = ws2[p * 256 + kcl * 128 + 64 + ln];
#pragma unroll
                for (int pedi = 0; pedi < 2; ++pedi) {
                    short8 a2 = *(const short8*)&X1c[wv][pedi][c15][q8];
                    c2[pedi][0] = __builtin_amdgcn_mfma_f32_16x16x32_bf16(
                            a2, w20, c2[pedi][0], 0, 0, 0);
                    c2[pedi][1] = __builtin_amdgcn_mfma_f32_16x16x32_bf16(
                            a2, w21, c2[pedi][1], 0, 0, 0);
                }
            }
        }
    }

    // ---- epilogue per ped (wave-private LDS; r9-verified logic) ----
    for (int pedi = 0; pedi < 2; ++pedi) {
#pragma unroll
        for (int nt2 = 0; nt2 < 2; ++nt2) {
            const float bb2 = b2[nt2 * 16 + c15];
#pragma unroll
            for (int r = 0; r < 4; ++r)
                X2s[wv][((ln >> 4) * 4 + r) * 32 + nt2 * 16 + c15] =
                    fmaxf(c2[pedi][nt2][r] + bb2, 0.f);
        }
        {
            int t = c15, g = ln >> 4;
            float lg = 0.f;
            for (int k = g * 128; k < g * 128 + 128; ++k)
                lg += X2s[wv][k] * Wa[k * MAXP + t];
            lg += __shfl_xor(lg, 16, 64);
            lg += __shfl_xor(lg, 32, 64);
            if (ln < 16) LG[wv][ln] = lg + ba[ln];
        }
        float mx = -1e30f;
#pragma unroll
        for (int m = 0; m < MAXP; ++m) mx = fmaxf(mx, LG[wv][m]);
        float sum = 0.f;
#pragma unroll
        for (int m = 0; m < MAXP; ++m) sum += expf(LG[wv][m] - mx);
        if (ln < 16) WS[wv][ln] = expf(LG[wv][ln] - mx) / sum;
        if (ln < BN) {
            float o = 0.f;
#pragma unroll
            for (int m = 0; m < MAXP; ++m) o += WS[wv][m] * X2s[wv][m * BN + ln];
            out[(base + il0 + pedi) * BN + ln] = o;
        }
    }
}

// Fallback (ws too small): r11-verified LDS-staging version, inline cvt.
__global__ __launch_bounds__(256, 2) void fused_fb(
    const float* __restrict__ h_states, const float* __restrict__ last_pos,
    const float* __restrict__ Wpos,     const float* __restrict__ bpos,
    const float* __restrict__ W1,       const float* __restrict__ b1,
    const float* __restrict__ W2,       const float* __restrict__ b2,
    const float* __restrict__ Wa,       const float* __restrict__ ba,
    float* __restrict__ out)
{
    __shared__ short8 fb1[1024];
    __shared__ short8 fb2[256];
    __shared__ unsigned short X1c[4][16][40];
    __shared__ float X2s[4][512];
    __shared__ float px[N_PED], py[N_PED];
    __shared__ float LG[4][16], WS[4][16];

    const int tid = threadIdx.x;
    const int wv  = tid >> 6;
    const int ln  = tid & 63;
    const int q8  = (ln >> 4) << 3;
    const int c15 = ln & 15;
    const int s    = blockIdx.x / 25;
    const int base = s * N_PED;
    const int il0  = (blockIdx.x % 25) * 8 + wv * 2;

    if (tid < N_PED) {
        px[tid] = last_pos[(base + tid) * 2 + 0];
        py[tid] = last_pos[(base + tid) * 2 + 1];
    }
    __syncthreads();

    short8  af[2][4];
    floatx4 c2[2][2] = {};
    for (int pedi = 0; pedi < 2; ++pedi) {
        const int il = il0 + pedi;
        const float xi = px[il], yi = py[il];
        const int mm = c15, qq = ln >> 4;
        int cnt;
        {
            float dxm = __fsub_rn(px[mm], xi), dym = __fsub_rn(py[mm], yi);
            float dm = __fsqrt_rn(__builtin_fmaf(dxm, dxm, __fmul_rn(dym, dym)));
            cnt = 0;
            for (int j = qq * 50; j < qq * 50 + 50; ++j) {
                float dx = __fsub_rn(px[j], xi), dy = __fsub_rn(py[j], yi);
                float dj = __fsqrt_rn(__builtin_fmaf(dx, dx, __fmul_rn(dy, dy)));
                cnt += (dj < dm || (dj == dm && j < mm)) ? 1 : 0;
            }
            cnt += __shfl_xor(cnt, 16, 64);
            cnt += __shfl_xor(cnt, 32, 64);
        }
        const int sm = cnt;
#pragma unroll
        for (int ks = 0; ks < 2; ++ks) {
            const float* hp = &h_states[(base + sm) * 64 + ks * 32 + q8];
            short8 v;
#pragma unroll
            for (int j = 0; j < 8; ++j) v[j] = f2bu(hp[j]);
            af[pedi][ks] = v;
        }
        const float fx = px[sm] - xi, fy = py[sm] - yi;
#pragma unroll
        for (int ks = 2; ks < 4; ++ks) {
            int e0 = (ks - 2) * 32 + q8;
            short8 v;
#pragma unroll
            for (int j = 0; j < 8; ++j) {
                float e = fx * Wpos[e0 + j] + fy * Wpos[64 + e0 + j] + bpos[e0 + j];
                v[j] = f2bu(e);
            }
            af[pedi][ks] = v;
        }
    }

    for (int p = 0; p < 8; ++p) {
        __syncthreads();
        for (int f = tid; f < 1024; f += 256) {
            int lane = f & 63, ks = (f >> 6) & 3, nt = f >> 8;
            int n  = p * 64 + nt * 16 + (lane & 15);
            int k0 = ks * 32 + ((lane >> 4) << 3);
            short8 v;
#pragma unroll
            for (int j = 0; j < 8; ++j) v[j] = f2bu(W1[(k0 + j) * HID + n]);
            fb1[f] = v;
        }
        {
            int lane = tid & 63, nt2 = (tid >> 6) & 1, kcl = tid >> 7;
            int kc = p * 2 + kcl;
            int n  = nt2 * 16 + (lane & 15);
            int k0 = kc * 32 + ((lane >> 4) << 3);
            short8 v;
#pragma unroll
            for (int j = 0; j < 8; ++j) v[j] = f2bu(W2[(k0 + j) * BN + n]);
            fb2[tid] = v;
        }
        __syncthreads();
#pragma unroll
        for (int pedi = 0; pedi < 2; ++pedi) {
#pragma unroll
            for (int ntl = 0; ntl < 4; ++ntl) {
                const int nt = p * 4 + ntl;
                floatx4 c = {};
#pragma unroll
                for (int ks = 0; ks < 4; ++ks)
                    c = __builtin_amdgcn_mfma_f32_16x16x32_bf16(
                            af[pedi][ks], fb1[ntl * 256 + ks * 64 + ln], c, 0, 0, 0);
                const float bb = b1[nt * 16 + c15];
                const int colb = (ntl & 1) * 16 + c15;
#pragma unroll
                for (int r = 0; r < 4; ++r)
                    X1c[wv][(ln >> 4) * 4 + r][colb] =
                        (unsigned short)f2bu(fmaxf(c[r] + bb, 0.f));
                if (ntl & 1) {
                    const int kcl = ntl >> 1;
                    short8 a2 = *(const short8*)&X1c[wv][c15][q8];
                    c2[pedi][0] = __builtin_amdgcn_mfma_f32_16x16x32_bf16(
                            a2, fb2[kcl * 128 + ln], c2[pedi][0], 0, 0, 0);
                    c2[pedi][1] = __builtin_amdgcn_mfma_f32_16x16x32_bf16(
                            a2, fb2[kcl * 128 + 64 + ln], c2[pedi][1], 0, 0, 0);
                }
            }
        }
    }

    for (int pedi = 0; pedi < 2; ++pedi) {
#pragma unroll
        for (int nt2 = 0; nt2 < 2; ++nt2) {
            const float bb2 = b2[nt2 * 16 + c15];
#pragma unroll
            for (int r = 0; r < 4; ++r)
                X2s[wv][((ln >> 4) * 4 + r) * 32 + nt2 * 16 + c15] =
                    fmaxf(c2[pedi][nt2][r] + bb2, 0.f);
        }
        {
            int t = c15, g = ln >> 4;
            float lg = 0.f;
            for (int k = g * 128; k < g * 128 + 128; ++k)
                lg += X2s[wv][k] * Wa[k * MAXP + t];
            lg += __shfl_xor(lg, 16, 64);
            lg += __shfl_xor(lg, 32, 64);
            if (ln < 16) LG[wv][ln] = lg + ba[ln];
        }
        float mx = -1e30f;
#pragma unroll
        for (int m = 0; m < MAXP; ++m) mx = fmaxf(mx, LG[wv][m]);
        float sum = 0.f;
#pragma unroll
        for (int m = 0; m < MAXP; ++m) sum += expf(LG[wv][m] - mx);
        if (ln < 16) WS[wv][ln] = expf(LG[wv][ln] - mx) / sum;
        if (ln < BN) {
            float o = 0.f;
#pragma unroll
            for (int m = 0; m < MAXP; ++m) o += WS[wv][m] * X2s[wv][m * BN + ln];
            out[(base + il0 + pedi) * BN + ln] = o;
        }
    }
}

extern "C" void kernel_launch(void* const* d_in, const int* in_sizes, int n_in,
                              void* d_out, int out_size, void* d_ws, size_t ws_size,
                              hipStream_t stream) {
    const float* h_states = (const float*)d_in[0];
    const float* last_pos = (const float*)d_in[1];
    const float* Wpos     = (const float*)d_in[2];
    const float* bpos     = (const float*)d_in[3];
    const float* W1       = (const float*)d_in[4];
    const float* b1       = (const float*)d_in[5];
    const float* W2       = (const float*)d_in[6];
    const float* b2       = (const float*)d_in[7];
    const float* Wa       = (const float*)d_in[8];
    const float* ba       = (const float*)d_in[9];
    // d_in[10] seq_start_end, d_in[11] train_or_test: structurally constant, unused

    short8* ws1 = (short8*)d_ws;
    short8* ws2 = ws1 + WS1_FRAGS;
    const int grid = (S_CNT * N_PED) / 8;          // 6250

    if (ws_size >= WS_NEED) {
        cvt_kernel<<<40, 256, 0, stream>>>(W1, W2, ws1, ws2);
        fused_pre<<<grid, 256, 0, stream>>>(
            h_states, last_pos, Wpos, bpos, b1, b2, Wa, ba, ws1, ws2, (float*)d_out);
    } else {
        fused_fb<<<grid, 256, 0, stream>>>(
            h_states, last_pos, Wpos, bpos, W1, b1, W2, b2, Wa, ba, (float*)d_out);
    }
}